// Round 6
// baseline (81.691 us; speedup 1.0000x reference)
//
#include <hip/hip_runtime.h>
#include <hip/hip_bf16.h>
#include <math.h>

#define BATCH  16384
#define XDIM   18
#define LATENT 16
#define NM     128
#define KDIM   4096
#define OUTF   64
#define KB     32
#define BM     32

typedef short s16x8 __attribute__((ext_vector_type(8)));
typedef float f32x16 __attribute__((ext_vector_type(16)));

__device__ __forceinline__ unsigned short f2bf(float f) {
    union { float f; unsigned u; } v; v.f = f;
    return (unsigned short)((v.u + 0x7FFFu + ((v.u >> 16) & 1u)) >> 16);
}
__device__ __forceinline__ unsigned pack_bf2(float a, float b) {
    __hip_bfloat162 h = __float22bfloat162_rn(make_float2(a, b));  // v_cvt_pk_bf16_f32
    return *(unsigned*)&h;
}
// swap bits 2 and 3 (the sigma' map: hacc C-row -> k index) — HW-verified r4/r5
__device__ __forceinline__ int swap23(int m) {
    return (m & ~12) | ((m & 4) << 1) | ((m & 8) >> 1);
}

// ---------------------------------------------------------------------------
// Precompute (unchanged, proven r4/r5): W_eff -> wfrag (B-frag layout),
// fc1_w -> f1frag (A-frag layout, sigma-permuted cols), fc1_b -> bh
// (hacc/C-layout, sigma-permuted), b_eff.
// wfrag:  [kc 0..255][ct 0..3][lane 0..63][8 bf16]
// f1frag: [jt 0..127][lane 0..63][8 bf16]
// ---------------------------------------------------------------------------
__global__ __launch_bounds__(128) void precompute_kernel(
    const float* __restrict__ x, const float* __restrict__ fc1_w,
    const float* __restrict__ fc1_b, const float* __restrict__ fc2_w,
    const float* __restrict__ fc2_b, const float* __restrict__ dil,
    const float* __restrict__ shf, unsigned short* __restrict__ wfrag,
    unsigned short* __restrict__ f1frag, float* __restrict__ bh,
    float* __restrict__ beff)
{
    const int tid = threadIdx.x;
    const int bid = blockIdx.x;
    if (bid < 512) {
        __shared__ float basis[KB];
        __shared__ float bred[32];
        if (tid < KB) {
            const float s   = x[(size_t)(BATCH - 1) * XDIM + 1];
            const float arg = s * dil[0] + shf[0];
            const float n   = 16.0f * (float)(tid & 15) / 15.0f;
            const float a   = arg * n;
            basis[tid] = (tid < 16) ? cosf(a) : sinf(a);
        }
        __syncthreads();
        const int m  = bid >> 2, kq = bid & 3;
        const int k8 = kq * 128 + tid;
        const int k  = k8 * 8;
        float acc[8] = {0.f,0.f,0.f,0.f,0.f,0.f,0.f,0.f};
        const float* src = fc2_w + (size_t)m * KB * KDIM + k;
        #pragma unroll 4
        for (int kb = 0; kb < KB; ++kb) {
            const float wgt = basis[kb];
            const float4 a = *(const float4*)(src + (size_t)kb * KDIM);
            const float4 b = *(const float4*)(src + (size_t)kb * KDIM + 4);
            acc[0] = fmaf(wgt, a.x, acc[0]); acc[1] = fmaf(wgt, a.y, acc[1]);
            acc[2] = fmaf(wgt, a.z, acc[2]); acc[3] = fmaf(wgt, a.w, acc[3]);
            acc[4] = fmaf(wgt, b.x, acc[4]); acc[5] = fmaf(wgt, b.y, acc[5]);
            acc[6] = fmaf(wgt, b.z, acc[6]); acc[7] = fmaf(wgt, b.w, acc[7]);
        }
        const int ct = m >> 5, coln = m & 31;
        const int kc = k8 >> 1, kg = k8 & 1;
        const int lane = kg * 32 + coln;
        unsigned short t[8];
        #pragma unroll
        for (int i = 0; i < 8; ++i) t[i] = f2bf(acc[i]);
        *(uint4*)(wfrag + ((size_t)(kc * 4 + ct) * 64 + lane) * 8) = *(const uint4*)t;
        if (kq == 0 && tid < 32) bred[tid] = basis[tid] * fc2_b[m * KB + tid];
        __syncthreads();
        if (kq == 0 && tid == 0) {
            float s = 0.f;
            #pragma unroll
            for (int i = 0; i < 32; ++i) s += bred[i];
            beff[m] = s;
        }
    } else if (bid < 576) {
        const int slot = (bid - 512) * 128 + tid;
        const int lane = slot & 63;
        const int jt   = slot >> 6;
        const int j    = jt * 32 + swap23(lane & 31);
        const int kg   = lane >> 5;
        const float* src = fc1_w + (size_t)j * LATENT + kg * 8;
        const float4 a = *(const float4*)(src);
        const float4 b = *(const float4*)(src + 4);
        unsigned short t[8];
        t[0]=f2bf(a.x); t[1]=f2bf(a.y); t[2]=f2bf(a.z); t[3]=f2bf(a.w);
        t[4]=f2bf(b.x); t[5]=f2bf(b.y); t[6]=f2bf(b.z); t[7]=f2bf(b.w);
        *(uint4*)(f1frag + (size_t)slot * 8) = *(const uint4*)t;
    } else {
        const int jt = tid;
        #pragma unroll
        for (int mp = 0; mp < 32; ++mp) {
            const int lg = mp >> 4, r = mp & 15;
            const int crow = (r & 3) + 8 * (r >> 2) + 4 * lg;
            bh[jt * 32 + mp] = fc1_b[jt * 32 + swap23(crow)];
        }
    }
}

// ---------------------------------------------------------------------------
// Fused: 512 blocks x 512 thr (8 waves, 2 blocks/CU), BM=32 rows.
// Wave ks (0..7) owns j-tiles ks*16..+16, ALL 4 ct tiles (acc[4], 64 VGPR).
// Per j-tile: prefetch 8 B-frags; hT mfma (bias-C from LDS) -> relu+cvt_pk
// -> 8 main MFMAs. hT computed once per (block, jt); no LDS/barriers in loop.
// Tail: sequential 8-pass ks-reduce in LDS + epilogue.
// ---------------------------------------------------------------------------
__global__ __launch_bounds__(512, 4) void fused_kernel(
    const float* __restrict__ x,
    const unsigned short* __restrict__ wfrag,
    const unsigned short* __restrict__ f1frag,
    const float* __restrict__ bh,
    const float* __restrict__ beff, float* __restrict__ out)
{
    __shared__ float bhs[128 * 32];    // 16 KB, bias in hacc layout
    __shared__ float wfull[BM * NM];   // 16 KB

    const int tid = threadIdx.x;
    const int ks  = tid >> 6, l = tid & 63;
    const int l31 = l & 31,  lg = l >> 5;
    const int row0 = blockIdx.x * BM;

    // stage bias table (16 KB) once
    {
        const float4* src = (const float4*)bh;
        float4* dst = (float4*)bhs;
        dst[tid]       = src[tid];
        dst[tid + 512] = src[tid + 512];
    }

    // zfrag: lane l holds z[row0 + l31][lg*8 + r]  (loop-invariant)
    s16x8 zfrag;
    {
        const float* zp = x + (size_t)(row0 + l31) * XDIM + 2 + lg * 8;
        #pragma unroll
        for (int q = 0; q < 4; ++q) {
            const float2 t = *(const float2*)(zp + 2 * q);
            ((unsigned*)&zfrag)[q] = pack_bf2(t.x, t.y);
        }
    }

    f32x16 acc[4];
    #pragma unroll
    for (int ct = 0; ct < 4; ++ct)
        #pragma unroll
        for (int i = 0; i < 16; ++i) acc[ct][i] = 0.0f;

    __syncthreads();   // bhs ready

    const unsigned short* fvp = f1frag + ((size_t)(ks * 16) * 64 + l) * 8;
    const float*          bhp = bhs + (ks * 16) * 32 + lg * 16;
    const unsigned short* bp  = wfrag + (size_t)ks * 65536 + l * 8;

    #pragma unroll 2
    for (int t = 0; t < 16; ++t) {
        // issue all loads first: 8 B-frags (32 regs) fly under hT + repack
        s16x8 B[8];
        #pragma unroll
        for (int i = 0; i < 8; ++i) B[i] = *(const s16x8*)(bp + (size_t)i * 512);
        const uint4 fv = *(const uint4*)(fvp);
        const float4 c0 = *(const float4*)(bhp);
        const float4 c1 = *(const float4*)(bhp + 4);
        const float4 c2 = *(const float4*)(bhp + 8);
        const float4 c3 = *(const float4*)(bhp + 12);
        fvp += 512; bhp += 32; bp += 4096;

        f32x16 hc;
        hc[0]=c0.x;  hc[1]=c0.y;  hc[2]=c0.z;  hc[3]=c0.w;
        hc[4]=c1.x;  hc[5]=c1.y;  hc[6]=c1.z;  hc[7]=c1.w;
        hc[8]=c2.x;  hc[9]=c2.y;  hc[10]=c2.z; hc[11]=c2.w;
        hc[12]=c3.x; hc[13]=c3.y; hc[14]=c3.z; hc[15]=c3.w;
        hc = __builtin_amdgcn_mfma_f32_32x32x16_bf16(*(const s16x8*)&fv, zfrag, hc, 0, 0, 0);

        unsigned a0[4], a1[4];
        #pragma unroll
        for (int q = 0; q < 4; ++q) {
            a0[q] = pack_bf2(fmaxf(hc[2*q],   0.f), fmaxf(hc[2*q+1],   0.f));
            a1[q] = pack_bf2(fmaxf(hc[8+2*q], 0.f), fmaxf(hc[8+2*q+1], 0.f));
        }
        #pragma unroll
        for (int ct = 0; ct < 4; ++ct) {
            acc[ct] = __builtin_amdgcn_mfma_f32_32x32x16_bf16(*(const s16x8*)a0, B[ct],     acc[ct], 0, 0, 0);
            acc[ct] = __builtin_amdgcn_mfma_f32_32x32x16_bf16(*(const s16x8*)a1, B[4 + ct], acc[ct], 0, 0, 0);
        }
    }

    // deterministic sequential ks-reduce through LDS + b_eff
    #pragma unroll 1
    for (int p = 0; p < 8; ++p) {
        if (ks == p) {
            #pragma unroll
            for (int ct = 0; ct < 4; ++ct) {
                const float be = beff[ct * 32 + l31];
                #pragma unroll
                for (int r = 0; r < 16; ++r) {
                    const int rowl = (r & 3) + 8 * (r >> 2) + 4 * lg;
                    const int idx  = rowl * NM + ct * 32 + l31;
                    wfull[idx] = (p == 0) ? (acc[ct][r] + be) : (wfull[idx] + acc[ct][r]);
                }
            }
        }
        __syncthreads();
    }

    // out[b,o] = inp[b] * w[b,o] + w[b,64+o]
    {
        const int o = tid & 63, rg = tid >> 6;
        #pragma unroll
        for (int i = 0; i < 4; ++i) {
            const int r = rg * 4 + i;
            const float inp = x[(size_t)(row0 + r) * XDIM];
            out[(size_t)(row0 + r) * OUTF + o] =
                fmaf(inp, wfull[r * NM + o], wfull[r * NM + OUTF + o]);
        }
    }
}

// ---------------------------------------------------------------------------
extern "C" void kernel_launch(void* const* d_in, const int* in_sizes, int n_in,
                              void* d_out, int out_size, void* d_ws, size_t ws_size,
                              hipStream_t stream) {
    const float* x     = (const float*)d_in[0];
    const float* fc1_w = (const float*)d_in[1];
    const float* fc1_b = (const float*)d_in[2];
    const float* fc2_w = (const float*)d_in[3];
    const float* fc2_b = (const float*)d_in[4];
    const float* dil   = (const float*)d_in[5];
    const float* shf   = (const float*)d_in[6];
    float* out = (float*)d_out;

    // ws: wfrag 1 MB | f1frag 128 KB | beff 512 B | bh 16 KB
    unsigned short* wfrag  = (unsigned short*)d_ws;
    unsigned short* f1frag = wfrag + 524288;
    float*          beff   = (float*)(f1frag + 65536);
    float*          bh     = beff + NM;

    precompute_kernel<<<577, 128, 0, stream>>>(x, fc1_w, fc1_b, fc2_w, fc2_b,
                                               dil, shf, wfrag, f1frag, bh, beff);
    fused_kernel<<<BATCH / BM, 512, 0, stream>>>(x, wfrag, f1frag, bh, beff, out);
}

// Round 7
// 48.695 us; speedup vs baseline: 1.6776x; 1.6776x over previous
//
#include <hip/hip_runtime.h>
#include <hip/hip_bf16.h>
#include <math.h>

#define BATCH  16384
#define XDIM   18
#define LATENT 16
#define NM     128
#define KDIM   4096
#define OUTF   64
#define KB     32
#define BM     64

typedef short s16x8 __attribute__((ext_vector_type(8)));
typedef float f32x16 __attribute__((ext_vector_type(16)));

__device__ __forceinline__ unsigned short f2bf(float f) {
    union { float f; unsigned u; } v; v.f = f;
    return (unsigned short)((v.u + 0x7FFFu + ((v.u >> 16) & 1u)) >> 16);
}
__device__ __forceinline__ unsigned pack_bf2(float a, float b) {
    __hip_bfloat162 h = __float22bfloat162_rn(make_float2(a, b));  // v_cvt_pk_bf16_f32
    return *(unsigned*)&h;
}
// swap bits 2 and 3 (the sigma' map: hacc C-row -> k index) — HW-verified r4-r6
__device__ __forceinline__ int swap23(int m) {
    return (m & ~12) | ((m & 4) << 1) | ((m & 8) >> 1);
}

// ---------------------------------------------------------------------------
// Precompute (unchanged, proven r4-r6): W_eff -> wfrag (B-frag layout),
// fc1_w -> f1frag (A-frag layout, sigma-permuted cols), fc1_b -> bh
// (hacc/C-layout, sigma-permuted), b_eff.
// wfrag:  [kc 0..255][ct 0..3][lane 0..63][8 bf16]
// f1frag: [jt 0..127][lane 0..63][8 bf16]
// ---------------------------------------------------------------------------
__global__ __launch_bounds__(128) void precompute_kernel(
    const float* __restrict__ x, const float* __restrict__ fc1_w,
    const float* __restrict__ fc1_b, const float* __restrict__ fc2_w,
    const float* __restrict__ fc2_b, const float* __restrict__ dil,
    const float* __restrict__ shf, unsigned short* __restrict__ wfrag,
    unsigned short* __restrict__ f1frag, float* __restrict__ bh,
    float* __restrict__ beff)
{
    const int tid = threadIdx.x;
    const int bid = blockIdx.x;
    if (bid < 512) {
        __shared__ float basis[KB];
        __shared__ float bred[32];
        if (tid < KB) {
            const float s   = x[(size_t)(BATCH - 1) * XDIM + 1];
            const float arg = s * dil[0] + shf[0];
            const float n   = 16.0f * (float)(tid & 15) / 15.0f;
            const float a   = arg * n;
            basis[tid] = (tid < 16) ? cosf(a) : sinf(a);
        }
        __syncthreads();
        const int m  = bid >> 2, kq = bid & 3;
        const int k8 = kq * 128 + tid;
        const int k  = k8 * 8;
        float acc[8] = {0.f,0.f,0.f,0.f,0.f,0.f,0.f,0.f};
        const float* src = fc2_w + (size_t)m * KB * KDIM + k;
        #pragma unroll 4
        for (int kb = 0; kb < KB; ++kb) {
            const float wgt = basis[kb];
            const float4 a = *(const float4*)(src + (size_t)kb * KDIM);
            const float4 b = *(const float4*)(src + (size_t)kb * KDIM + 4);
            acc[0] = fmaf(wgt, a.x, acc[0]); acc[1] = fmaf(wgt, a.y, acc[1]);
            acc[2] = fmaf(wgt, a.z, acc[2]); acc[3] = fmaf(wgt, a.w, acc[3]);
            acc[4] = fmaf(wgt, b.x, acc[4]); acc[5] = fmaf(wgt, b.y, acc[5]);
            acc[6] = fmaf(wgt, b.z, acc[6]); acc[7] = fmaf(wgt, b.w, acc[7]);
        }
        const int ct = m >> 5, coln = m & 31;
        const int kc = k8 >> 1, kg = k8 & 1;
        const int lane = kg * 32 + coln;
        unsigned short t[8];
        #pragma unroll
        for (int i = 0; i < 8; ++i) t[i] = f2bf(acc[i]);
        *(uint4*)(wfrag + ((size_t)(kc * 4 + ct) * 64 + lane) * 8) = *(const uint4*)t;
        if (kq == 0 && tid < 32) bred[tid] = basis[tid] * fc2_b[m * KB + tid];
        __syncthreads();
        if (kq == 0 && tid == 0) {
            float s = 0.f;
            #pragma unroll
            for (int i = 0; i < 32; ++i) s += bred[i];
            beff[m] = s;
        }
    } else if (bid < 576) {
        const int slot = (bid - 512) * 128 + tid;
        const int lane = slot & 63;
        const int jt   = slot >> 6;
        const int j    = jt * 32 + swap23(lane & 31);
        const int kg   = lane >> 5;
        const float* src = fc1_w + (size_t)j * LATENT + kg * 8;
        const float4 a = *(const float4*)(src);
        const float4 b = *(const float4*)(src + 4);
        unsigned short t[8];
        t[0]=f2bf(a.x); t[1]=f2bf(a.y); t[2]=f2bf(a.z); t[3]=f2bf(a.w);
        t[4]=f2bf(b.x); t[5]=f2bf(b.y); t[6]=f2bf(b.z); t[7]=f2bf(b.w);
        *(uint4*)(f1frag + (size_t)slot * 8) = *(const uint4*)t;
    } else {
        const int jt = tid;
        #pragma unroll
        for (int mp = 0; mp < 32; ++mp) {
            const int lg = mp >> 4, r = mp & 15;
            const int crow = (r & 3) + 8 * (r >> 2) + 4 * lg;
            bh[jt * 32 + mp] = fc1_b[jt * 32 + swap23(crow)];
        }
    }
}

// ---------------------------------------------------------------------------
// Fused: 256 blocks x 1024 thr (16 waves, 1 block/CU, 4 waves/SIMD), BM=64.
// Wave = (rt, ctp, ks): rows rt*32..+32, cols ctp*64..+64 (ct pair), j-tiles
// ks*32..+32. Per iter: 4 B-frags + 1 A-frag prefetched one iter ahead
// (explicit register double-buffer, static names); hT mfma (bias-C from LDS)
// -> relu+cvt_pk -> 4 main MFMAs into acc0/acc1. rt-pair waves read the SAME
// B stream ~simultaneously -> L1 absorbs the 2x. No LDS/barriers in loop.
// Tail: 4-pass sequential ks-reduce + epilogue.
// ---------------------------------------------------------------------------
__global__ __launch_bounds__(1024, 4) void fused_kernel(
    const float* __restrict__ x,
    const unsigned short* __restrict__ wfrag,
    const unsigned short* __restrict__ f1frag,
    const float* __restrict__ bh,
    const float* __restrict__ beff, float* __restrict__ out)
{
    __shared__ float bhs[128 * 32];    // 16 KB bias table (hacc layout)
    __shared__ float wfull[BM * NM];   // 32 KB

    const int tid = threadIdx.x;
    const int w   = tid >> 6, l = tid & 63;
    const int l31 = l & 31,  lg = l >> 5;
    const int row0 = blockIdx.x * BM;
    const int rt = w & 1, ctp = (w >> 1) & 1, ks = w >> 2;

    // stage bias table (16 KB == 1024 float4, one per thread)
    ((float4*)bhs)[tid] = ((const float4*)bh)[tid];

    // zfrag: lane l holds z[row0 + rt*32 + l31][lg*8 + r]  (loop-invariant)
    s16x8 zfrag;
    {
        const float* zp = x + (size_t)(row0 + rt * 32 + l31) * XDIM + 2 + lg * 8;
        #pragma unroll
        for (int q = 0; q < 4; ++q) {
            const float2 t = *(const float2*)(zp + 2 * q);
            ((unsigned*)&zfrag)[q] = pack_bf2(t.x, t.y);
        }
    }

    f32x16 acc0, acc1;
    #pragma unroll
    for (int i = 0; i < 16; ++i) { acc0[i] = 0.0f; acc1[i] = 0.0f; }

    __syncthreads();   // bhs ready

    // per-iter strides: fvp +512 us, bp +4096 us (kc0 advances by 2), bhp +32
    const unsigned short* fvp = f1frag + ((size_t)(ks * 32) * 64 + l) * 8;
    const float*          bhp = bhs + (ks * 32) * 32 + lg * 16;
    const unsigned short* bp  = wfrag + ((size_t)(2 * (ks * 32)) * 4 + 2 * ctp) * 512 + l * 8;

    auto compute = [&](const uint4& fv, const s16x8& B0, const s16x8& B1,
                       const s16x8& B2, const s16x8& B3, const float* bq) {
        const float4 c0 = *(const float4*)(bq);
        const float4 c1 = *(const float4*)(bq + 4);
        const float4 c2 = *(const float4*)(bq + 8);
        const float4 c3 = *(const float4*)(bq + 12);
        f32x16 hc;
        hc[0]=c0.x;  hc[1]=c0.y;  hc[2]=c0.z;  hc[3]=c0.w;
        hc[4]=c1.x;  hc[5]=c1.y;  hc[6]=c1.z;  hc[7]=c1.w;
        hc[8]=c2.x;  hc[9]=c2.y;  hc[10]=c2.z; hc[11]=c2.w;
        hc[12]=c3.x; hc[13]=c3.y; hc[14]=c3.z; hc[15]=c3.w;
        hc = __builtin_amdgcn_mfma_f32_32x32x16_bf16(*(const s16x8*)&fv, zfrag, hc, 0, 0, 0);
        unsigned a0[4], a1[4];
        #pragma unroll
        for (int q = 0; q < 4; ++q) {
            a0[q] = pack_bf2(fmaxf(hc[2*q],   0.f), fmaxf(hc[2*q+1],   0.f));
            a1[q] = pack_bf2(fmaxf(hc[8+2*q], 0.f), fmaxf(hc[8+2*q+1], 0.f));
        }
        acc0 = __builtin_amdgcn_mfma_f32_32x32x16_bf16(*(const s16x8*)a0, B0, acc0, 0, 0, 0);
        acc1 = __builtin_amdgcn_mfma_f32_32x32x16_bf16(*(const s16x8*)a0, B1, acc1, 0, 0, 0);
        acc0 = __builtin_amdgcn_mfma_f32_32x32x16_bf16(*(const s16x8*)a1, B2, acc0, 0, 0, 0);
        acc1 = __builtin_amdgcn_mfma_f32_32x32x16_bf16(*(const s16x8*)a1, B3, acc1, 0, 0, 0);
    };

    // prologue: load iter 0 into set A
    uint4 fvA = *(const uint4*)(fvp);
    s16x8 B0A = *(const s16x8*)(bp);
    s16x8 B1A = *(const s16x8*)(bp + 512);
    s16x8 B2A = *(const s16x8*)(bp + 2048);
    s16x8 B3A = *(const s16x8*)(bp + 2560);

    // hand-unrolled x2 software pipeline, static register names (rule #20).
    // Trailing prefetches read past this wave's region into adjacent d_ws
    // buffers (valid memory) and are never consumed.
    for (int t = 0; t < 32; t += 2) {
        const uint4 fvB = *(const uint4*)(fvp + 512);
        const s16x8 B0B = *(const s16x8*)(bp + 4096);
        const s16x8 B1B = *(const s16x8*)(bp + 4096 + 512);
        const s16x8 B2B = *(const s16x8*)(bp + 4096 + 2048);
        const s16x8 B3B = *(const s16x8*)(bp + 4096 + 2560);
        compute(fvA, B0A, B1A, B2A, B3A, bhp);

        fvA = *(const uint4*)(fvp + 1024);
        B0A = *(const s16x8*)(bp + 8192);
        B1A = *(const s16x8*)(bp + 8192 + 512);
        B2A = *(const s16x8*)(bp + 8192 + 2048);
        B3A = *(const s16x8*)(bp + 8192 + 2560);
        compute(fvB, B0B, B1B, B2B, B3B, bhp + 32);

        fvp += 1024; bp += 8192; bhp += 64;
    }

    // deterministic sequential ks-reduce through LDS + b_eff (4 passes)
    #pragma unroll 1
    for (int p = 0; p < 4; ++p) {
        if (ks == p) {
            const float be0 = beff[(2 * ctp) * 32 + l31];
            const float be1 = beff[(2 * ctp + 1) * 32 + l31];
            #pragma unroll
            for (int r = 0; r < 16; ++r) {
                const int rowl = (r & 3) + 8 * (r >> 2) + 4 * lg;
                const int idx  = (rt * 32 + rowl) * NM + (2 * ctp) * 32 + l31;
                if (p == 0) {
                    wfull[idx]      = acc0[r] + be0;
                    wfull[idx + 32] = acc1[r] + be1;
                } else {
                    wfull[idx]      += acc0[r];
                    wfull[idx + 32] += acc1[r];
                }
            }
        }
        __syncthreads();
    }

    // out[b,o] = inp[b] * w[b,o] + w[b,64+o]
    {
        const int o = tid & 63, rg = tid >> 6;
        #pragma unroll
        for (int i = 0; i < 4; ++i) {
            const int r = rg * 4 + i;
            const float inp = x[(size_t)(row0 + r) * XDIM];
            out[(size_t)(row0 + r) * OUTF + o] =
                fmaf(inp, wfull[r * NM + o], wfull[r * NM + OUTF + o]);
        }
    }
}

// ---------------------------------------------------------------------------
extern "C" void kernel_launch(void* const* d_in, const int* in_sizes, int n_in,
                              void* d_out, int out_size, void* d_ws, size_t ws_size,
                              hipStream_t stream) {
    const float* x     = (const float*)d_in[0];
    const float* fc1_w = (const float*)d_in[1];
    const float* fc1_b = (const float*)d_in[2];
    const float* fc2_w = (const float*)d_in[3];
    const float* fc2_b = (const float*)d_in[4];
    const float* dil   = (const float*)d_in[5];
    const float* shf   = (const float*)d_in[6];
    float* out = (float*)d_out;

    // ws: wfrag 1 MB | f1frag 128 KB | beff 512 B | bh 16 KB
    unsigned short* wfrag  = (unsigned short*)d_ws;
    unsigned short* f1frag = wfrag + 524288;
    float*          beff   = (float*)(f1frag + 65536);
    float*          bh     = beff + NM;

    precompute_kernel<<<577, 128, 0, stream>>>(x, fc1_w, fc1_b, fc2_w, fc2_b,
                                               dil, shf, wfrag, f1frag, bh, beff);
    fused_kernel<<<BATCH / BM, 1024, 0, stream>>>(x, wfrag, f1frag, bh, beff, out);
}